// Round 13
// baseline (225.995 us; speedup 1.0000x reference)
//
#include <hip/hip_runtime.h>
#include <hip/hip_fp16.h>

// DiffusionConv: out = x@Tf0 + Px@(Tb0+Tb1) + P2x@(Tf1+Tb2) + P3x@Tf2
// R13: col-tiled prop gathers. build sorts each node's bucket by col
// (LDS insertion sort) and packs per-node tile offsets (4 tiles of 16384
// cols = 2MB x-slice, fits per-XCD L2). prop sweeps tiles in order so all
// resident waves gather from one L2-hot slice at a time. Gather count
// unchanged -- only locality. Rest = R12 (fused scatter2, LDS build,
// MFMA gemm, fp16 features).

#define N_NODES 50000
#define N_EDGES 800000
#define C 64
#define CAP 64          // bucket capacity; rows ~ Poisson(16), P(>64) ~ 2e-18
#define NPART 196       // partitions of 256 rows: p = r >> 8
#define CAPP 4608       // edges per partition region; mean 4096, +8 sigma
#define EPB 8192        // edges per block in scatter2
#define NEB 98          // ceil(800000/8192)
#define XH_BLOCKS 782   // ceil(800000 float4 chunks / 1024)
#define CW_BLOCKS 16    // 16384 weight elems / 1024

typedef _Float16 half8 __attribute__((ext_vector_type(8)));
typedef float f32x4 __attribute__((ext_vector_type(4)));

// Fused: blocks [0,NEB): hist+reserve+scatter; [NEB,NEB+XH): x fp32->fp16;
// [NEB+XH,..): combined weights -> fp16 transposed whc[j][co][ci]
__global__ __launch_bounds__(1024) void scatter2_kernel(
        const int* __restrict__ row, const int* __restrict__ col,
        const float* __restrict__ w, int* __restrict__ percur,
        uint2* __restrict__ pedges,
        const float* __restrict__ x, __half* __restrict__ xh,
        const float* __restrict__ tf, const float* __restrict__ tb,
        _Float16* __restrict__ whc) {
    const int tid = threadIdx.x;
    if (blockIdx.x >= NEB + XH_BLOCKS) {
        int idx = (blockIdx.x - NEB - XH_BLOCKS) * 1024 + tid;  // < 16384
        int j = idx >> 12;
        int rem = idx & 4095;   // ci*64 + co
        int ci = rem >> 6;
        int co = rem & 63;
        float v;
        if (j == 0)      v = tf[rem];                         // Tf0
        else if (j == 1) v = tb[rem] + tb[4096 + rem];        // Tb0 + Tb1
        else if (j == 2) v = tf[4096 + rem] + tb[8192 + rem]; // Tf1 + Tb2
        else             v = tf[8192 + rem];                  // Tf2
        whc[(j << 12) + (co << 6) + ci] = (_Float16)v;        // transposed
        return;
    }
    if (blockIdx.x >= NEB) {
        int i = (blockIdx.x - NEB) * 1024 + tid;
        if (i < N_NODES * C / 4) {
            float4 v = ((const float4*)x)[i];
            union { float2 f2; __half2 h2[2]; } u;
            u.h2[0] = __floats2half2_rn(v.x, v.y);
            u.h2[1] = __floats2half2_rn(v.z, v.w);
            ((float2*)xh)[i] = u.f2;
        }
        return;
    }
    __shared__ int h[NPART];
    __shared__ int cur[NPART];
    uint2 ent[8];
    int pp[8];
    if (tid < NPART) h[tid] = 0;
    __syncthreads();
    int base = blockIdx.x * EPB;
#pragma unroll
    for (int i = 0; i < 8; ++i) {
        int e = base + i * 1024 + tid;
        pp[i] = -1;
        if (e < N_EDGES) {
            int r = row[e];
            unsigned int c = (unsigned int)col[e];
            unsigned int wh = (unsigned int)__half_as_ushort(__float2half_rn(w[e]));
            ent[i] = make_uint2((c << 16) | wh, (unsigned int)(r & 255));
            pp[i] = r >> 8;
            atomicAdd(&h[pp[i]], 1);
        }
    }
    __syncthreads();
    if (tid < NPART) cur[tid] = atomicAdd(&percur[tid], h[tid]);
    __syncthreads();
#pragma unroll
    for (int i = 0; i < 8; ++i) {
        if (pp[i] >= 0) {
            int slot = atomicAdd(&cur[pp[i]], 1);
            pedges[(size_t)pp[i] * CAPP + slot] = ent[i];
        }
    }
}

// One block per partition: LDS-bin 256 rows x 64 slots, SORT each row by
// col, pack tile offsets (4 tiles of 16384 cols) + m into cpk, fuse dinv,
// dump buckets contiguously.
__global__ __launch_bounds__(1024) void build_kernel(
        const uint2* __restrict__ pedges, const int* __restrict__ percur,
        unsigned int* __restrict__ bkt, unsigned int* __restrict__ cpk,
        float* __restrict__ dinv) {
    __shared__ unsigned int lbuck[256 * CAP];   // 64 KB
    __shared__ int lcnt[256];
    const int tid = threadIdx.x;
    const int p = blockIdx.x;
    if (tid < 256) lcnt[tid] = 0;
    __syncthreads();
    int e = min(percur[p], CAPP);
    const uint2* src = pedges + (size_t)p * CAPP;
    for (int i = tid; i < e; i += 1024) {
        uint2 en = src[i];
        int rl = (int)en.y;
        int slot = atomicAdd(&lcnt[rl], 1);
        if (slot < CAP) lbuck[(rl << 6) + slot] = en.x;
    }
    __syncthreads();
    if (tid < 256) {
        int m = min(lcnt[tid], CAP);
        unsigned int* rowp = &lbuck[tid << 6];
        // insertion sort by col (entry >> 16)
        for (int i = 1; i < m; ++i) {
            unsigned int key = rowp[i];
            int j = i - 1;
            while (j >= 0 && (rowp[j] >> 16) > (key >> 16)) {
                rowp[j + 1] = rowp[j];
                --j;
            }
            rowp[j + 1] = key;
        }
        // tile offsets (cols < 16384 / 32768 / 49152) + dinv sum
        int o1 = 0, o2 = 0, o3 = 0;
        float sum = 0.f;
        for (int j = 0; j < m; ++j) {
            unsigned int c = rowp[j] >> 16;
            o1 += (c < 16384u);
            o2 += (c < 32768u);
            o3 += (c < 49152u);
            sum += __half2float(__ushort_as_half((unsigned short)(rowp[j] & 0xFFFFu)));
        }
        int g = (p << 8) + tid;
        if (g < N_NODES) {
            cpk[g] = (unsigned int)o1 | ((unsigned int)o2 << 8) |
                     ((unsigned int)o3 << 16) | ((unsigned int)m << 24);
            dinv[g] = (sum > 0.f) ? rsqrtf(sum) : 0.f;
        }
    }
    __syncthreads();
    // contiguous 64 KB dump (uint4-vectorized)
    const uint4* s4 = (const uint4*)lbuck;
    uint4* dst = (uint4*)(bkt + ((size_t)p << 14));
    for (int i = tid; i < 256 * CAP / 4; i += 1024) dst[i] = s4[i];
}

// one col-tile's worth of edges for one node (quarter-wave q, lane ql)
__device__ __forceinline__ void prop_span(
        const __half* __restrict__ xin, const unsigned int* __restrict__ bktrow,
        const float* __restrict__ dinv, int q, int ql, int s, int e2,
        float& ax, float& ay, float& az, float& aw) {
    for (int cb = s; cb < e2; cb += 16) {
        int cj = 0;
        float nj = 0.f;
        int idx = cb + ql;
        if (idx < e2) {
            unsigned int b = bktrow[idx];
            int c = (int)(b >> 16);
            cj = c << 6;                                   // half-elem row offset
            nj = __half2float(__ushort_as_half((unsigned short)(b & 0xFFFFu))) * dinv[c];
        }
        int rem = e2 - cb;
        if (rem > 16) rem = 16;
        int mm = (rem + 7) & ~7;    // padded lanes carry cj=0,nj=0
        for (int jo = 0; jo < mm; jo += 8) {
            int cs[8];
            float ns[8];
            float2 vs[8];
#pragma unroll
            for (int t = 0; t < 8; ++t) {
                cs[t] = __shfl(cj, (q << 4) + jo + t);
                ns[t] = __shfl(nj, (q << 4) + jo + t);
            }
#pragma unroll
            for (int t = 0; t < 8; ++t)
                vs[t] = *(const float2*)(xin + cs[t] + (ql << 2));
#pragma unroll
            for (int t = 0; t < 8; ++t) {
                const __half2* hp = (const __half2*)&vs[t];
                float2 a = __half22float2(hp[0]);
                float2 b = __half22float2(hp[1]);
                ax += ns[t] * a.x;
                ay += ns[t] * a.y;
                az += ns[t] * b.x;
                aw += ns[t] * b.y;
            }
        }
    }
}

// 4 nodes per wave; tile sweep: all waves process col-tile 0 (x rows
// 0..16383, 2MB slice -> L2-hot) before tile 1, etc.
__global__ __launch_bounds__(256) void prop_kernel(
        const __half* __restrict__ xin, __half* __restrict__ xout,
        const unsigned int* __restrict__ cpk, const unsigned int* __restrict__ bkt,
        const float* __restrict__ dinv) {
    int wave = (blockIdx.x * blockDim.x + threadIdx.x) >> 6;
    int lane = threadIdx.x & 63;
    int q = lane >> 4;
    int ql = lane & 15;
    int node = (wave << 2) + q;     // 12500 waves * 4 = 50000 exactly
    if (node >= N_NODES) return;
    unsigned int po = cpk[node];
    int b1 = (int)(po & 255u);
    int b2 = (int)((po >> 8) & 255u);
    int b3 = (int)((po >> 16) & 255u);
    int b4 = (int)(po >> 24);
    const unsigned int* bktrow = bkt + ((size_t)node << 6);
    float ax = 0.f, ay = 0.f, az = 0.f, aw = 0.f;
    prop_span(xin, bktrow, dinv, q, ql, 0,  b1, ax, ay, az, aw);
    prop_span(xin, bktrow, dinv, q, ql, b1, b2, ax, ay, az, aw);
    prop_span(xin, bktrow, dinv, q, ql, b2, b3, ax, ay, az, aw);
    prop_span(xin, bktrow, dinv, q, ql, b3, b4, ax, ay, az, aw);
    float dr = dinv[node];
    union { float2 f2; __half2 h2[2]; } u;
    u.h2[0] = __floats2half2_rn(dr * ax, dr * ay);
    u.h2[1] = __floats2half2_rn(dr * az, dr * aw);
    *(float2*)(xout + ((size_t)node << 6) + (ql << 2)) = u.f2;
}

// MFMA GEMM: out[r][co] = sum_j Xj[r][:] @ Wc[j][:][co], K=4*64.
// A-frag: A[m=lane&15][k=quad*8+i] from xh row (16B).
// B-frag: B[k=quad*8+i][n=lane&15] from whc[j][n][k..] (transposed, 16B).
// C/D: col=lane&15, row=quad*4+reg.
__global__ __launch_bounds__(256) void gemm_mfma_kernel(
        const __half* __restrict__ x0, const __half* __restrict__ x1,
        const __half* __restrict__ x2, const __half* __restrict__ x3,
        const _Float16* __restrict__ whc, float* __restrict__ out) {
    const int tid = threadIdx.x;
    const int wv = tid >> 6;
    const int lane = tid & 63;
    const int quad = lane >> 4;
    const int l16 = lane & 15;
    const int mbase = (blockIdx.x << 6) + (wv << 4);
    const __half* srcs[4] = {x0, x1, x2, x3};
    f32x4 acc0 = {}, acc1 = {}, acc2 = {}, acc3 = {};
    const int arow = mbase + l16;
    const bool aok = arow < N_NODES;
    const size_t abase = ((size_t)arow << 6) + (quad << 3);
    const half8 zero8 = {};
#pragma unroll
    for (int j = 0; j < 4; ++j) {
        const __half* src = srcs[j];
#pragma unroll
        for (int kk = 0; kk < 64; kk += 32) {
            half8 af = aok ? *(const half8*)(const void*)(src + abase + kk) : zero8;
            const _Float16* wb = whc + (j << 12) + kk + (quad << 3);
            half8 b0 = *(const half8*)(const void*)(wb + ((0 * 16 + l16) << 6));
            half8 b1 = *(const half8*)(const void*)(wb + ((1 * 16 + l16) << 6));
            half8 b2 = *(const half8*)(const void*)(wb + ((2 * 16 + l16) << 6));
            half8 b3 = *(const half8*)(const void*)(wb + ((3 * 16 + l16) << 6));
            acc0 = __builtin_amdgcn_mfma_f32_16x16x32_f16(af, b0, acc0, 0, 0, 0);
            acc1 = __builtin_amdgcn_mfma_f32_16x16x32_f16(af, b1, acc1, 0, 0, 0);
            acc2 = __builtin_amdgcn_mfma_f32_16x16x32_f16(af, b2, acc2, 0, 0, 0);
            acc3 = __builtin_amdgcn_mfma_f32_16x16x32_f16(af, b3, acc3, 0, 0, 0);
        }
    }
#pragma unroll
    for (int i = 0; i < 4; ++i) {
        int r = mbase + (quad << 2) + i;
        if (r < N_NODES) {
            float* dst = out + ((size_t)r << 6) + l16;
            dst[0]  = acc0[i];
            dst[16] = acc1[i];
            dst[32] = acc2[i];
            dst[48] = acc3[i];
        }
    }
}

extern "C" void kernel_launch(void* const* d_in, const int* in_sizes, int n_in,
                              void* d_out, int out_size, void* d_ws, size_t ws_size,
                              hipStream_t stream) {
    const float* x  = (const float*)d_in[0];
    const int*   ei = (const int*)d_in[1];   // row = ei[0..E), col = ei[E..2E)
    const float* ew = (const float*)d_in[2];
    const float* tf = (const float*)d_in[3];
    const float* tb = (const float*)d_in[4];
    float* out = (float*)d_out;

    const int* row = ei;
    const int* col = ei + N_EDGES;

    // workspace layout (4B words), total ~46 MB
    const int NROWS_PAD = NPART * 256;   // 50176
    float* ws = (float*)d_ws;
    size_t off = 0;
    int*    percur = (int*)(ws + off); off += 256;
    uint2*  pedges = (uint2*)(ws + off); off += (size_t)NPART * CAPP * 2;
    unsigned int* bkt = (unsigned int*)(ws + off); off += (size_t)NROWS_PAD * CAP;
    unsigned int* cpk = (unsigned int*)(ws + off); off += NROWS_PAD;
    float*  dinv = ws + off; off += NROWS_PAD;
    __half* xh   = (__half*)(ws + off); off += (size_t)N_NODES * C / 2;
    __half* tA   = (__half*)(ws + off); off += (size_t)N_NODES * C / 2;
    __half* tB   = (__half*)(ws + off); off += (size_t)N_NODES * C / 2;
    __half* tC   = (__half*)(ws + off); off += (size_t)N_NODES * C / 2;
    _Float16* whc = (_Float16*)(ws + off); off += 4 * 64 * 64 / 2;

    hipMemsetAsync(percur, 0, NPART * sizeof(int), stream);

    scatter2_kernel<<<NEB + XH_BLOCKS + CW_BLOCKS, 1024, 0, stream>>>(
        row, col, ew, percur, pedges, x, xh, tf, tb, whc);
    build_kernel<<<NPART, 1024, 0, stream>>>(pedges, percur, bkt, cpk, dinv);

    const int PB = (N_NODES + 15) / 16;   // 4 nodes/wave, 4 waves/block
    prop_kernel<<<PB, 256, 0, stream>>>(xh, tA, cpk, bkt, dinv);   // tx1
    prop_kernel<<<PB, 256, 0, stream>>>(tA, tB, cpk, bkt, dinv);   // tx2
    prop_kernel<<<PB, 256, 0, stream>>>(tB, tC, cpk, bkt, dinv);   // tx3

    const int GB = (N_NODES + 63) / 64;
    gemm_mfma_kernel<<<GB, 256, 0, stream>>>(xh, tA, tB, tC, whc, out);
}

// Round 14
// 165.214 us; speedup vs baseline: 1.3679x; 1.3679x over previous
//
#include <hip/hip_runtime.h>
#include <hip/hip_fp16.h>

// DiffusionConv: out = x@Tf0 + Px@(Tb0+Tb1) + P2x@(Tf1+Tb2) + P3x@Tf2
// R14: revert R13's col-sort (build hit 6.9M LDS bank conflicts: stride-64
// rows alias one bank set; span-split also shrank prop's gather pipeline).
// = R12 pipeline (fused scatter2 -> LDS build -> 3 props -> MFMA gemm)
// + prop prefetches its <=4 strided bucket entries upfront (all meta loads
// in flight; masked lanes contribute 0).

#define N_NODES 50000
#define N_EDGES 800000
#define C 64
#define CAP 64          // bucket capacity; rows ~ Poisson(16), P(>64) ~ 2e-18
#define NPART 196       // partitions of 256 rows: p = r >> 8
#define CAPP 4608       // edges per partition region; mean 4096, +8 sigma
#define EPB 8192        // edges per block in scatter2
#define NEB 98          // ceil(800000/8192)
#define XH_BLOCKS 782   // ceil(800000 float4 chunks / 1024)
#define CW_BLOCKS 16    // 16384 weight elems / 1024

typedef _Float16 half8 __attribute__((ext_vector_type(8)));
typedef float f32x4 __attribute__((ext_vector_type(4)));

// Fused: blocks [0,NEB): hist+reserve+scatter; [NEB,NEB+XH): x fp32->fp16;
// [NEB+XH,..): combined weights -> fp16 transposed whc[j][co][ci]
__global__ __launch_bounds__(1024) void scatter2_kernel(
        const int* __restrict__ row, const int* __restrict__ col,
        const float* __restrict__ w, int* __restrict__ percur,
        uint2* __restrict__ pedges,
        const float* __restrict__ x, __half* __restrict__ xh,
        const float* __restrict__ tf, const float* __restrict__ tb,
        _Float16* __restrict__ whc) {
    const int tid = threadIdx.x;
    if (blockIdx.x >= NEB + XH_BLOCKS) {
        int idx = (blockIdx.x - NEB - XH_BLOCKS) * 1024 + tid;  // < 16384
        int j = idx >> 12;
        int rem = idx & 4095;   // ci*64 + co
        int ci = rem >> 6;
        int co = rem & 63;
        float v;
        if (j == 0)      v = tf[rem];                         // Tf0
        else if (j == 1) v = tb[rem] + tb[4096 + rem];        // Tb0 + Tb1
        else if (j == 2) v = tf[4096 + rem] + tb[8192 + rem]; // Tf1 + Tb2
        else             v = tf[8192 + rem];                  // Tf2
        whc[(j << 12) + (co << 6) + ci] = (_Float16)v;        // transposed
        return;
    }
    if (blockIdx.x >= NEB) {
        int i = (blockIdx.x - NEB) * 1024 + tid;
        if (i < N_NODES * C / 4) {
            float4 v = ((const float4*)x)[i];
            union { float2 f2; __half2 h2[2]; } u;
            u.h2[0] = __floats2half2_rn(v.x, v.y);
            u.h2[1] = __floats2half2_rn(v.z, v.w);
            ((float2*)xh)[i] = u.f2;
        }
        return;
    }
    __shared__ int h[NPART];
    __shared__ int cur[NPART];
    uint2 ent[8];
    int pp[8];
    if (tid < NPART) h[tid] = 0;
    __syncthreads();
    int base = blockIdx.x * EPB;
#pragma unroll
    for (int i = 0; i < 8; ++i) {
        int e = base + i * 1024 + tid;
        pp[i] = -1;
        if (e < N_EDGES) {
            int r = row[e];
            unsigned int c = (unsigned int)col[e];
            unsigned int wh = (unsigned int)__half_as_ushort(__float2half_rn(w[e]));
            ent[i] = make_uint2((c << 16) | wh, (unsigned int)(r & 255));
            pp[i] = r >> 8;
            atomicAdd(&h[pp[i]], 1);
        }
    }
    __syncthreads();
    if (tid < NPART) cur[tid] = atomicAdd(&percur[tid], h[tid]);
    __syncthreads();
#pragma unroll
    for (int i = 0; i < 8; ++i) {
        if (pp[i] >= 0) {
            int slot = atomicAdd(&cur[pp[i]], 1);
            pedges[(size_t)pp[i] * CAPP + slot] = ent[i];
        }
    }
}

// One block per partition: LDS-bin 256 rows x 64 slots, fuse dinv,
// dump buckets contiguously.
__global__ __launch_bounds__(1024) void build_kernel(
        const uint2* __restrict__ pedges, const int* __restrict__ percur,
        unsigned int* __restrict__ bkt, int* __restrict__ cnt,
        float* __restrict__ dinv) {
    __shared__ unsigned int lbuck[256 * CAP];   // 64 KB
    __shared__ int lcnt[256];
    const int tid = threadIdx.x;
    const int p = blockIdx.x;
    if (tid < 256) lcnt[tid] = 0;
    __syncthreads();
    int e = min(percur[p], CAPP);
    const uint2* src = pedges + (size_t)p * CAPP;
    for (int i = tid; i < e; i += 1024) {
        uint2 en = src[i];
        int rl = (int)en.y;
        int slot = atomicAdd(&lcnt[rl], 1);
        if (slot < CAP) lbuck[(rl << 6) + slot] = en.x;
    }
    __syncthreads();
    if (tid < 256) {
        int m = min(lcnt[tid], CAP);
        int g = (p << 8) + tid;
        float sum = 0.f;
        for (int j = 0; j < m; ++j)
            sum += __half2float(__ushort_as_half(
                (unsigned short)(lbuck[(tid << 6) + j] & 0xFFFFu)));
        if (g < N_NODES) {
            cnt[g] = m;
            dinv[g] = (sum > 0.f) ? rsqrtf(sum) : 0.f;
        }
    }
    __syncthreads();
    // contiguous 64 KB dump (uint4-vectorized)
    const uint4* s4 = (const uint4*)lbuck;
    uint4* dst = (uint4*)(bkt + ((size_t)p << 14));
    for (int i = tid; i < 256 * CAP / 4; i += 1024) dst[i] = s4[i];
}

// 4 nodes per wave: quarter-wave q owns node wave*4+q; lane ql (0-15) holds
// channels 4ql..4ql+3. Bucket meta prefetched upfront (<=4 entries/lane, all
// loads in flight); 8B x-gathers; dinv[col] per edge; dinv[row] at epilogue.
__global__ __launch_bounds__(256) void prop_kernel(
        const __half* __restrict__ xin, __half* __restrict__ xout,
        const int* __restrict__ cnt, const unsigned int* __restrict__ bkt,
        const float* __restrict__ dinv) {
    int wave = (blockIdx.x * blockDim.x + threadIdx.x) >> 6;
    int lane = threadIdx.x & 63;
    int q = lane >> 4;
    int ql = lane & 15;
    int node = (wave << 2) + q;     // 12500 waves * 4 = 50000 exactly
    if (node >= N_NODES) return;
    int m = min(cnt[node], CAP);
    int base = node << 6;
    // prefetch all (<=4) strided bucket entries for this lane
    int cj[4];
    float nj[4];
#pragma unroll
    for (int s = 0; s < 4; ++s) {
        int idx = (s << 4) + ql;
        cj[s] = 0;
        nj[s] = 0.f;
        if (idx < m) {
            unsigned int b = bkt[base + idx];
            int c = (int)(b >> 16);
            cj[s] = c << 6;                                // half-elem row offset
            nj[s] = __half2float(__ushort_as_half((unsigned short)(b & 0xFFFFu))) * dinv[c];
        }
    }
    float ax = 0.f, ay = 0.f, az = 0.f, aw = 0.f;
#pragma unroll
    for (int s = 0; s < 4; ++s) {
        int cb = s << 4;
        if (cb >= m) break;
        int rem = m - cb;
        if (rem > 16) rem = 16;
        int mm = (rem + 7) & ~7;    // padded lanes carry cj=0,nj=0
        for (int jo = 0; jo < mm; jo += 8) {
            int cs[8];
            float ns[8];
            float2 vs[8];
#pragma unroll
            for (int t = 0; t < 8; ++t) {
                cs[t] = __shfl(cj[s], (q << 4) + jo + t);
                ns[t] = __shfl(nj[s], (q << 4) + jo + t);
            }
#pragma unroll
            for (int t = 0; t < 8; ++t)
                vs[t] = *(const float2*)(xin + cs[t] + (ql << 2));
#pragma unroll
            for (int t = 0; t < 8; ++t) {
                const __half2* hp = (const __half2*)&vs[t];
                float2 a = __half22float2(hp[0]);
                float2 b = __half22float2(hp[1]);
                ax += ns[t] * a.x;
                ay += ns[t] * a.y;
                az += ns[t] * b.x;
                aw += ns[t] * b.y;
            }
        }
    }
    float dr = dinv[node];
    union { float2 f2; __half2 h2[2]; } u;
    u.h2[0] = __floats2half2_rn(dr * ax, dr * ay);
    u.h2[1] = __floats2half2_rn(dr * az, dr * aw);
    *(float2*)(xout + base + (ql << 2)) = u.f2;
}

// MFMA GEMM: out[r][co] = sum_j Xj[r][:] @ Wc[j][:][co], K=4*64.
// A-frag: A[m=lane&15][k=quad*8+i] from xh row (16B).
// B-frag: B[k=quad*8+i][n=lane&15] from whc[j][n][k..] (transposed, 16B).
// C/D: col=lane&15, row=quad*4+reg.
__global__ __launch_bounds__(256) void gemm_mfma_kernel(
        const __half* __restrict__ x0, const __half* __restrict__ x1,
        const __half* __restrict__ x2, const __half* __restrict__ x3,
        const _Float16* __restrict__ whc, float* __restrict__ out) {
    const int tid = threadIdx.x;
    const int wv = tid >> 6;
    const int lane = tid & 63;
    const int quad = lane >> 4;
    const int l16 = lane & 15;
    const int mbase = (blockIdx.x << 6) + (wv << 4);
    const __half* srcs[4] = {x0, x1, x2, x3};
    f32x4 acc0 = {}, acc1 = {}, acc2 = {}, acc3 = {};
    const int arow = mbase + l16;
    const bool aok = arow < N_NODES;
    const size_t abase = ((size_t)arow << 6) + (quad << 3);
    const half8 zero8 = {};
#pragma unroll
    for (int j = 0; j < 4; ++j) {
        const __half* src = srcs[j];
#pragma unroll
        for (int kk = 0; kk < 64; kk += 32) {
            half8 af = aok ? *(const half8*)(const void*)(src + abase + kk) : zero8;
            const _Float16* wb = whc + (j << 12) + kk + (quad << 3);
            half8 b0 = *(const half8*)(const void*)(wb + ((0 * 16 + l16) << 6));
            half8 b1 = *(const half8*)(const void*)(wb + ((1 * 16 + l16) << 6));
            half8 b2 = *(const half8*)(const void*)(wb + ((2 * 16 + l16) << 6));
            half8 b3 = *(const half8*)(const void*)(wb + ((3 * 16 + l16) << 6));
            acc0 = __builtin_amdgcn_mfma_f32_16x16x32_f16(af, b0, acc0, 0, 0, 0);
            acc1 = __builtin_amdgcn_mfma_f32_16x16x32_f16(af, b1, acc1, 0, 0, 0);
            acc2 = __builtin_amdgcn_mfma_f32_16x16x32_f16(af, b2, acc2, 0, 0, 0);
            acc3 = __builtin_amdgcn_mfma_f32_16x16x32_f16(af, b3, acc3, 0, 0, 0);
        }
    }
#pragma unroll
    for (int i = 0; i < 4; ++i) {
        int r = mbase + (quad << 2) + i;
        if (r < N_NODES) {
            float* dst = out + ((size_t)r << 6) + l16;
            dst[0]  = acc0[i];
            dst[16] = acc1[i];
            dst[32] = acc2[i];
            dst[48] = acc3[i];
        }
    }
}

extern "C" void kernel_launch(void* const* d_in, const int* in_sizes, int n_in,
                              void* d_out, int out_size, void* d_ws, size_t ws_size,
                              hipStream_t stream) {
    const float* x  = (const float*)d_in[0];
    const int*   ei = (const int*)d_in[1];   // row = ei[0..E), col = ei[E..2E)
    const float* ew = (const float*)d_in[2];
    const float* tf = (const float*)d_in[3];
    const float* tb = (const float*)d_in[4];
    float* out = (float*)d_out;

    const int* row = ei;
    const int* col = ei + N_EDGES;

    // workspace layout (4B words), total ~46 MB
    const int NROWS_PAD = NPART * 256;   // 50176
    float* ws = (float*)d_ws;
    size_t off = 0;
    int*    percur = (int*)(ws + off); off += 256;
    uint2*  pedges = (uint2*)(ws + off); off += (size_t)NPART * CAPP * 2;
    unsigned int* bkt = (unsigned int*)(ws + off); off += (size_t)NROWS_PAD * CAP;
    int*    cnt  = (int*)(ws + off); off += NROWS_PAD;
    float*  dinv = ws + off; off += NROWS_PAD;
    __half* xh   = (__half*)(ws + off); off += (size_t)N_NODES * C / 2;
    __half* tA   = (__half*)(ws + off); off += (size_t)N_NODES * C / 2;
    __half* tB   = (__half*)(ws + off); off += (size_t)N_NODES * C / 2;
    __half* tC   = (__half*)(ws + off); off += (size_t)N_NODES * C / 2;
    _Float16* whc = (_Float16*)(ws + off); off += 4 * 64 * 64 / 2;

    hipMemsetAsync(percur, 0, NPART * sizeof(int), stream);

    scatter2_kernel<<<NEB + XH_BLOCKS + CW_BLOCKS, 1024, 0, stream>>>(
        row, col, ew, percur, pedges, x, xh, tf, tb, whc);
    build_kernel<<<NPART, 1024, 0, stream>>>(pedges, percur, bkt, cnt, dinv);

    const int PB = (N_NODES + 15) / 16;   // 4 nodes/wave, 4 waves/block
    prop_kernel<<<PB, 256, 0, stream>>>(xh, tA, cnt, bkt, dinv);   // tx1
    prop_kernel<<<PB, 256, 0, stream>>>(tA, tB, cnt, bkt, dinv);   // tx2
    prop_kernel<<<PB, 256, 0, stream>>>(tB, tC, cnt, bkt, dinv);   // tx3

    const int GB = (N_NODES + 63) / 64;
    gemm_mfma_kernel<<<GB, 256, 0, stream>>>(xh, tA, tB, tC, whc, out);
}